// Round 2
// baseline (276.163 us; speedup 1.0000x reference)
//
#include <hip/hip_runtime.h>
#include <math.h>

// Problem constants (fixed by reference setup_inputs)
constexpr int Bn = 4096, Sn = 256, Tn = 64;
constexpr int Dn = 18, Hn = 16, Ln = 3;
constexpr float EPS = 1e-5f;

// d_out layout: x_recon (B,S,D) | x_pred (B,T,D) | prob (B,1) | z_seq (B,S,L)
constexpr size_t OFF_XP   = (size_t)Bn * Sn * Dn;            // 18874368
constexpr size_t OFF_PROB = OFF_XP + (size_t)Bn * Tn * Dn;   // 23592960
constexpr size_t OFF_ZS   = OFF_PROB + (size_t)Bn;           // 23597056

__device__ __forceinline__ float fast_tanh(float x) {
    float ax = fabsf(x);
    float e  = __expf(-2.0f * ax);
    float r  = (1.0f - e) / (1.0f + e);
    return copysignf(r, x);
}

// K1: fused encode -> z_seq -> decode -> x_recon, plus z_mean reduce + classifier.
// One block per batch element b; thread s handles sequence position s.
__global__ __launch_bounds__(256) void k1_encdec(
    const float* __restrict__ x,
    const float* __restrict__ ew1, const float* __restrict__ eb1,
    const float* __restrict__ eg,  const float* __restrict__ ebb,
    const float* __restrict__ em,  const float* __restrict__ ev,
    const float* __restrict__ ew2, const float* __restrict__ eb2,
    const float* __restrict__ dw1, const float* __restrict__ db1,
    const float* __restrict__ dg,  const float* __restrict__ dbn,
    const float* __restrict__ dm,  const float* __restrict__ dv,
    const float* __restrict__ dw2, const float* __restrict__ db2,
    const float* __restrict__ cw1, const float* __restrict__ cb1,
    const float* __restrict__ cw2, const float* __restrict__ cb2,
    float* __restrict__ xrec, float* __restrict__ prob, float* __restrict__ zseq)
{
    const int b = blockIdx.x;
    const int s = threadIdx.x;
    const size_t row = (size_t)b * Sn + s;

    // Fold BN (applied post-ReLU) into scale/shift, once per block.
    __shared__ float esc[Hn], esh[Hn], dsc[Hn], dsh[Hn];
    if (s < Hn) {
        float sc = eg[s] / sqrtf(ev[s] + EPS);
        esc[s] = sc; esh[s] = ebb[s] - em[s] * sc;
        float sd = dg[s] / sqrtf(dv[s] + EPS);
        dsc[s] = sd; dsh[s] = dbn[s] - dm[s] * sd;
    }
    __syncthreads();

    // Load x row (18 floats, 8B-aligned -> float2)
    float xv[Dn];
    const float2* xp = reinterpret_cast<const float2*>(x + row * Dn);
    #pragma unroll
    for (int i = 0; i < Dn / 2; ++i) { float2 t = xp[i]; xv[2*i] = t.x; xv[2*i+1] = t.y; }

    // encode layer 1 + BN
    float h[Hn];
    #pragma unroll
    for (int j = 0; j < Hn; ++j) {
        float a = eb1[j];
        #pragma unroll
        for (int k = 0; k < Dn; ++k) a = fmaf(ew1[j*Dn + k], xv[k], a);
        a = fmaxf(a, 0.0f);
        h[j] = fmaf(a, esc[j], esh[j]);
    }
    // encode layer 2 -> z
    float z0 = eb2[0], z1 = eb2[1], z2 = eb2[2];
    #pragma unroll
    for (int j = 0; j < Hn; ++j) {
        z0 = fmaf(ew2[0*Hn + j], h[j], z0);
        z1 = fmaf(ew2[1*Hn + j], h[j], z1);
        z2 = fmaf(ew2[2*Hn + j], h[j], z2);
    }
    // write z_seq
    float* zp = zseq + row * Ln;
    zp[0] = z0; zp[1] = z1; zp[2] = z2;

    // decode -> x_recon
    float h2[Hn];
    #pragma unroll
    for (int j = 0; j < Hn; ++j) {
        float a = fmaf(dw1[j*Ln + 0], z0, db1[j]);
        a = fmaf(dw1[j*Ln + 1], z1, a);
        a = fmaf(dw1[j*Ln + 2], z2, a);
        a = fmaxf(a, 0.0f);
        h2[j] = fmaf(a, dsc[j], dsh[j]);
    }
    float2* op = reinterpret_cast<float2*>(xrec + row * Dn);
    #pragma unroll
    for (int i = 0; i < Dn / 2; ++i) {
        float a0 = db2[2*i], a1 = db2[2*i + 1];
        #pragma unroll
        for (int j = 0; j < Hn; ++j) {
            a0 = fmaf(dw2[(2*i)*Hn + j],   h2[j], a0);
            a1 = fmaf(dw2[(2*i+1)*Hn + j], h2[j], a1);
        }
        op[i] = make_float2(a0, a1);
    }

    // z_mean reduction over S (wave shuffle + LDS combine)
    float r0 = z0, r1 = z1, r2 = z2;
    #pragma unroll
    for (int off = 32; off > 0; off >>= 1) {
        r0 += __shfl_down(r0, off);
        r1 += __shfl_down(r1, off);
        r2 += __shfl_down(r2, off);
    }
    __shared__ float red[4][3];
    const int lane = s & 63, wid = s >> 6;
    if (lane == 0) { red[wid][0] = r0; red[wid][1] = r1; red[wid][2] = r2; }
    __syncthreads();
    if (s == 0) {
        float m0 = (red[0][0] + red[1][0] + red[2][0] + red[3][0]) * (1.0f / Sn);
        float m1 = (red[0][1] + red[1][1] + red[2][1] + red[3][1]) * (1.0f / Sn);
        float m2 = (red[0][2] + red[1][2] + red[2][2] + red[3][2]) * (1.0f / Sn);
        float logit = cb2[0];
        #pragma unroll
        for (int j = 0; j < 4; ++j) {
            float a = fmaf(cw1[j*3 + 0], m0, cb1[j]);
            a = fmaf(cw1[j*3 + 1], m1, a);
            a = fmaf(cw1[j*3 + 2], m2, a);
            a = fmaxf(a, 0.0f);
            logit = fmaf(cw2[j], a, logit);
        }
        prob[b] = 1.0f / (1.0f + __expf(-logit));
    }
}

// K2: sequential ODE scan, one thread per batch element (4096 threads total).
// Writes z trajectory into the first 3 floats of each x_pred row (d_out as scratch).
__global__ __launch_bounds__(256) void k2_ode(
    const float* __restrict__ zseq,
    const float* __restrict__ ow1, const float* __restrict__ ob1,
    const float* __restrict__ ow2, const float* __restrict__ ob2,
    float* __restrict__ scratch)
{
    const int b = blockIdx.x * blockDim.x + threadIdx.x;
    const float* zp = zseq + ((size_t)b * Sn + (Sn - 1)) * Ln;
    float z0 = zp[0], z1 = zp[1], z2 = zp[2];

    // uniform weight loads -> scalar registers
    float w1[8][3], bb1[8], w2v[3][8], bb2[3];
    #pragma unroll
    for (int j = 0; j < 8; ++j) {
        bb1[j] = ob1[j];
        #pragma unroll
        for (int k = 0; k < 3; ++k) w1[j][k] = ow1[j*3 + k];
    }
    #pragma unroll
    for (int i = 0; i < 3; ++i) {
        bb2[i] = ob2[i];
        #pragma unroll
        for (int j = 0; j < 8; ++j) w2v[i][j] = ow2[i*8 + j];
    }

    float* op = scratch + (size_t)b * Tn * Dn;
    for (int t = 0; t < Tn; ++t) {
        float a[8];
        #pragma unroll
        for (int j = 0; j < 8; ++j) {
            float u = fmaf(w1[j][0], z0, bb1[j]);
            u = fmaf(w1[j][1], z1, u);
            u = fmaf(w1[j][2], z2, u);
            a[j] = fast_tanh(u);
        }
        float d0 = bb2[0], d1 = bb2[1], d2 = bb2[2];
        #pragma unroll
        for (int j = 0; j < 8; ++j) {
            d0 = fmaf(w2v[0][j], a[j], d0);
            d1 = fmaf(w2v[1][j], a[j], d1);
            d2 = fmaf(w2v[2][j], a[j], d2);
        }
        z0 = fmaf(0.1f, d0, z0);
        z1 = fmaf(0.1f, d1, z1);
        z2 = fmaf(0.1f, d2, z2);
        op[t*Dn + 0] = z0; op[t*Dn + 1] = z1; op[t*Dn + 2] = z2;
    }
}

// K3: decode x_pred rows in parallel. Each thread reads the z stashed in its own
// row (registers first), then overwrites the row with the 18 decoded values.
__global__ __launch_bounds__(256) void k3_decpred(
    const float* __restrict__ dw1, const float* __restrict__ db1,
    const float* __restrict__ dg,  const float* __restrict__ dbn,
    const float* __restrict__ dm,  const float* __restrict__ dv,
    const float* __restrict__ dw2, const float* __restrict__ db2,
    float* xpred)
{
    const int r = blockIdx.x * blockDim.x + threadIdx.x;

    __shared__ float dsc[Hn], dsh[Hn];
    if (threadIdx.x < Hn) {
        float sd = dg[threadIdx.x] / sqrtf(dv[threadIdx.x] + EPS);
        dsc[threadIdx.x] = sd;
        dsh[threadIdx.x] = dbn[threadIdx.x] - dm[threadIdx.x] * sd;
    }
    __syncthreads();

    float* rowp = xpred + (size_t)r * Dn;
    float z0 = rowp[0], z1 = rowp[1], z2 = rowp[2];

    float h2[Hn];
    #pragma unroll
    for (int j = 0; j < Hn; ++j) {
        float a = fmaf(dw1[j*Ln + 0], z0, db1[j]);
        a = fmaf(dw1[j*Ln + 1], z1, a);
        a = fmaf(dw1[j*Ln + 2], z2, a);
        a = fmaxf(a, 0.0f);
        h2[j] = fmaf(a, dsc[j], dsh[j]);
    }
    float2* op = reinterpret_cast<float2*>(rowp);
    #pragma unroll
    for (int i = 0; i < Dn / 2; ++i) {
        float a0 = db2[2*i], a1 = db2[2*i + 1];
        #pragma unroll
        for (int j = 0; j < Hn; ++j) {
            a0 = fmaf(dw2[(2*i)*Hn + j],   h2[j], a0);
            a1 = fmaf(dw2[(2*i+1)*Hn + j], h2[j], a1);
        }
        op[i] = make_float2(a0, a1);
    }
}

extern "C" void kernel_launch(void* const* d_in, const int* in_sizes, int n_in,
                              void* d_out, int out_size, void* d_ws, size_t ws_size,
                              hipStream_t stream)
{
    const float* x   = (const float*)d_in[0];
    // d_in[1] = t_span: only its length (T=64) matters; unused at runtime.
    const float* ew1 = (const float*)d_in[2];
    const float* eb1 = (const float*)d_in[3];
    const float* eg  = (const float*)d_in[4];
    const float* ebb = (const float*)d_in[5];
    const float* em  = (const float*)d_in[6];
    const float* ev  = (const float*)d_in[7];
    const float* ew2 = (const float*)d_in[8];
    const float* eb2 = (const float*)d_in[9];
    const float* dw1 = (const float*)d_in[10];
    const float* db1 = (const float*)d_in[11];
    const float* dg  = (const float*)d_in[12];
    const float* dbn = (const float*)d_in[13];
    const float* dm  = (const float*)d_in[14];
    const float* dv  = (const float*)d_in[15];
    const float* dw2 = (const float*)d_in[16];
    const float* db2 = (const float*)d_in[17];
    const float* ow1 = (const float*)d_in[18];
    const float* ob1 = (const float*)d_in[19];
    const float* ow2 = (const float*)d_in[20];
    const float* ob2 = (const float*)d_in[21];
    const float* cw1 = (const float*)d_in[22];
    const float* cb1 = (const float*)d_in[23];
    const float* cw2 = (const float*)d_in[24];
    const float* cb2 = (const float*)d_in[25];

    float* out   = (float*)d_out;
    float* xrec  = out;
    float* xpred = out + OFF_XP;
    float* prob  = out + OFF_PROB;
    float* zseq  = out + OFF_ZS;

    k1_encdec<<<dim3(Bn), dim3(Sn), 0, stream>>>(
        x, ew1, eb1, eg, ebb, em, ev, ew2, eb2,
        dw1, db1, dg, dbn, dm, dv, dw2, db2,
        cw1, cb1, cw2, cb2, xrec, prob, zseq);

    k2_ode<<<dim3(Bn / 256), dim3(256), 0, stream>>>(
        zseq, ow1, ob1, ow2, ob2, xpred);

    k3_decpred<<<dim3((Bn * Tn) / 256), dim3(256), 0, stream>>>(
        dw1, db1, dg, dbn, dm, dv, dw2, db2, xpred);
}

// Round 5
// 262.442 us; speedup vs baseline: 1.0523x; 1.0523x over previous
//
#include <hip/hip_runtime.h>
#include <math.h>

// Problem constants (fixed by reference setup_inputs)
constexpr int Bn = 4096, Sn = 256, Tn = 64;
constexpr int Dn = 18, Hn = 16, Ln = 3;
constexpr float EPS = 1e-5f;

// d_out layout: x_recon (B,S,D) | x_pred (B,T,D) | prob (B,1) | z_seq (B,S,L)
constexpr size_t OFF_XP   = (size_t)Bn * Sn * Dn;            // 18874368
constexpr size_t OFF_PROB = OFF_XP + (size_t)Bn * Tn * Dn;   // 23592960
constexpr size_t OFF_ZS   = OFF_PROB + (size_t)Bn;           // 23597056

__device__ __forceinline__ float fast_tanh(float x) {
    float ax = fabsf(x);
    float e  = __expf(-2.0f * ax);
    float r  = (1.0f - e) / (1.0f + e);
    return copysignf(r, x);
}

// K1: fused encode -> z_seq -> decode -> x_recon, plus z_mean reduce + classifier.
// One block per batch element b; thread s handles sequence position s.
// All global x/x_recon traffic goes through LDS so every global instr is a
// dense float4 (full-line) access; per-thread row access happens in LDS
// (stride 18 floats = 2-way bank aliasing = free on CDNA4).
__global__ __launch_bounds__(256) void k1_encdec(
    const float* __restrict__ x,
    const float* __restrict__ ew1, const float* __restrict__ eb1,
    const float* __restrict__ eg,  const float* __restrict__ ebb,
    const float* __restrict__ em,  const float* __restrict__ ev,
    const float* __restrict__ ew2, const float* __restrict__ eb2,
    const float* __restrict__ dw1, const float* __restrict__ db1,
    const float* __restrict__ dg,  const float* __restrict__ dbn,
    const float* __restrict__ dm,  const float* __restrict__ dv,
    const float* __restrict__ dw2, const float* __restrict__ db2,
    const float* __restrict__ cw1, const float* __restrict__ cb1,
    const float* __restrict__ cw2, const float* __restrict__ cb2,
    float* __restrict__ xrec, float* __restrict__ prob, float* __restrict__ zseq)
{
    const int b = blockIdx.x;
    const int s = threadIdx.x;
    constexpr int TILE_F  = Sn * Dn;      // 4608 floats = 18 KB
    constexpr int TILE_F4 = TILE_F / 4;   // 1152 float4

    __shared__ float xt[TILE_F];          // reused: x in, x_recon out
    __shared__ float esc[Hn], esh[Hn], dsc[Hn], dsh[Hn];
    __shared__ float red[4][3];

    if (s < Hn) {
        float sc = eg[s] / sqrtf(ev[s] + EPS);
        esc[s] = sc; esh[s] = ebb[s] - em[s] * sc;
        float sd = dg[s] / sqrtf(dv[s] + EPS);
        dsc[s] = sd; dsh[s] = dbn[s] - dm[s] * sd;
    }

    // Coalesced tile load: dense float4, every cache line fully used.
    const float4* xg  = reinterpret_cast<const float4*>(x + (size_t)b * TILE_F);
    float4*       xt4 = reinterpret_cast<float4*>(xt);
    #pragma unroll
    for (int i = s; i < TILE_F4; i += 256) xt4[i] = xg[i];
    __syncthreads();

    // Own row from LDS (2-way bank aliasing only).
    float xv[Dn];
    #pragma unroll
    for (int k = 0; k < Dn; ++k) xv[k] = xt[s * Dn + k];

    // encode layer 1 + folded BN
    float h[Hn];
    #pragma unroll
    for (int j = 0; j < Hn; ++j) {
        float a = eb1[j];
        #pragma unroll
        for (int k = 0; k < Dn; ++k) a = fmaf(ew1[j*Dn + k], xv[k], a);
        a = fmaxf(a, 0.0f);
        h[j] = fmaf(a, esc[j], esh[j]);
    }
    // encode layer 2 -> z
    float z0 = eb2[0], z1 = eb2[1], z2 = eb2[2];
    #pragma unroll
    for (int j = 0; j < Hn; ++j) {
        z0 = fmaf(ew2[0*Hn + j], h[j], z0);
        z1 = fmaf(ew2[1*Hn + j], h[j], z1);
        z2 = fmaf(ew2[2*Hn + j], h[j], z2);
    }
    // z_seq write: rows are 12 B and lane-contiguous -> already dense.
    float* zp = zseq + ((size_t)b * Sn + s) * Ln;
    zp[0] = z0; zp[1] = z1; zp[2] = z2;

    // decode -> x_recon (into registers, then own LDS row; no sync needed
    // since each thread reads/writes only its own row between barriers)
    float h2[Hn];
    #pragma unroll
    for (int j = 0; j < Hn; ++j) {
        float a = fmaf(dw1[j*Ln + 0], z0, db1[j]);
        a = fmaf(dw1[j*Ln + 1], z1, a);
        a = fmaf(dw1[j*Ln + 2], z2, a);
        a = fmaxf(a, 0.0f);
        h2[j] = fmaf(a, dsc[j], dsh[j]);
    }
    #pragma unroll
    for (int m = 0; m < Dn; ++m) {
        float a = db2[m];
        #pragma unroll
        for (int j = 0; j < Hn; ++j) a = fmaf(dw2[m*Hn + j], h2[j], a);
        xt[s * Dn + m] = a;
    }
    __syncthreads();

    // Coalesced tile store.
    float4* og = reinterpret_cast<float4*>(xrec + (size_t)b * TILE_F);
    #pragma unroll
    for (int i = s; i < TILE_F4; i += 256) og[i] = xt4[i];

    // z_mean reduction over S (wave shuffle + LDS combine)
    float r0 = z0, r1 = z1, r2 = z2;
    #pragma unroll
    for (int off = 32; off > 0; off >>= 1) {
        r0 += __shfl_down(r0, off);
        r1 += __shfl_down(r1, off);
        r2 += __shfl_down(r2, off);
    }
    const int lane = s & 63, wid = s >> 6;
    if (lane == 0) { red[wid][0] = r0; red[wid][1] = r1; red[wid][2] = r2; }
    __syncthreads();
    if (s == 0) {
        float m0 = (red[0][0] + red[1][0] + red[2][0] + red[3][0]) * (1.0f / Sn);
        float m1 = (red[0][1] + red[1][1] + red[2][1] + red[3][1]) * (1.0f / Sn);
        float m2 = (red[0][2] + red[1][2] + red[2][2] + red[3][2]) * (1.0f / Sn);
        float logit = cb2[0];
        #pragma unroll
        for (int j = 0; j < 4; ++j) {
            float a = fmaf(cw1[j*3 + 0], m0, cb1[j]);
            a = fmaf(cw1[j*3 + 1], m1, a);
            a = fmaf(cw1[j*3 + 2], m2, a);
            a = fmaxf(a, 0.0f);
            logit = fmaf(cw2[j], a, logit);
        }
        prob[b] = 1.0f / (1.0f + __expf(-logit));
    }
}

// K2: sequential ODE scan, one thread per batch element (4096 threads).
// zlayout 0: scratch is [t][B][3] in d_ws  -> per-step stores lane-contiguous.
// zlayout 1: fallback, stash z in first 12 B of each x_pred row.
__global__ __launch_bounds__(256) void k2_ode(
    const float* __restrict__ zseq,
    const float* __restrict__ ow1, const float* __restrict__ ob1,
    const float* __restrict__ ow2, const float* __restrict__ ob2,
    float* __restrict__ zscr, int zlayout)
{
    const int b = blockIdx.x * blockDim.x + threadIdx.x;
    const float* zp = zseq + ((size_t)b * Sn + (Sn - 1)) * Ln;
    float z0 = zp[0], z1 = zp[1], z2 = zp[2];

    float w1[8][3], bb1[8], w2v[3][8], bb2[3];
    #pragma unroll
    for (int j = 0; j < 8; ++j) {
        bb1[j] = ob1[j];
        #pragma unroll
        for (int k = 0; k < 3; ++k) w1[j][k] = ow1[j*3 + k];
    }
    #pragma unroll
    for (int i = 0; i < 3; ++i) {
        bb2[i] = ob2[i];
        #pragma unroll
        for (int j = 0; j < 8; ++j) w2v[i][j] = ow2[i*8 + j];
    }

    for (int t = 0; t < Tn; ++t) {
        float a[8];
        #pragma unroll
        for (int j = 0; j < 8; ++j) {
            float u = fmaf(w1[j][0], z0, bb1[j]);
            u = fmaf(w1[j][1], z1, u);
            u = fmaf(w1[j][2], z2, u);
            a[j] = fast_tanh(u);
        }
        float d0 = bb2[0], d1 = bb2[1], d2 = bb2[2];
        #pragma unroll
        for (int j = 0; j < 8; ++j) {
            d0 = fmaf(w2v[0][j], a[j], d0);
            d1 = fmaf(w2v[1][j], a[j], d1);
            d2 = fmaf(w2v[2][j], a[j], d2);
        }
        z0 = fmaf(0.1f, d0, z0);
        z1 = fmaf(0.1f, d1, z1);
        z2 = fmaf(0.1f, d2, z2);
        size_t idx = (zlayout == 0) ? ((size_t)t * Bn + b) * Ln
                                    : ((size_t)b * Tn + t) * Dn;
        zscr[idx + 0] = z0; zscr[idx + 1] = z1; zscr[idx + 2] = z2;
    }
}

// K3: decode x_pred rows. Block = 256 consecutive (b,t) rows; z read per
// thread (12 B, L2/L3-resident scratch, latency hidden by 1024-block TLP),
// outputs staged in LDS and stored as dense float4.
__global__ __launch_bounds__(256) void k3_decpred(
    const float* __restrict__ dw1, const float* __restrict__ db1,
    const float* __restrict__ dg,  const float* __restrict__ dbn,
    const float* __restrict__ dm,  const float* __restrict__ dv,
    const float* __restrict__ dw2, const float* __restrict__ db2,
    const float* __restrict__ zscr, int zlayout,
    float* __restrict__ xpred)
{
    const int r = blockIdx.x * blockDim.x + threadIdx.x;
    const int s = threadIdx.x;
    constexpr int TILE_F  = 256 * Dn;     // 4608 floats
    constexpr int TILE_F4 = TILE_F / 4;

    __shared__ float ot[TILE_F];
    __shared__ float dsc[Hn], dsh[Hn];
    if (s < Hn) {
        float sd = dg[s] / sqrtf(dv[s] + EPS);
        dsc[s] = sd;
        dsh[s] = dbn[s] - dm[s] * sd;
    }
    __syncthreads();

    const int bb = r / Tn, tt = r % Tn;
    size_t zidx = (zlayout == 0) ? ((size_t)tt * Bn + bb) * Ln
                                 : (size_t)r * Dn;
    float z0 = zscr[zidx + 0], z1 = zscr[zidx + 1], z2 = zscr[zidx + 2];

    float h2[Hn];
    #pragma unroll
    for (int j = 0; j < Hn; ++j) {
        float a = fmaf(dw1[j*Ln + 0], z0, db1[j]);
        a = fmaf(dw1[j*Ln + 1], z1, a);
        a = fmaf(dw1[j*Ln + 2], z2, a);
        a = fmaxf(a, 0.0f);
        h2[j] = fmaf(a, dsc[j], dsh[j]);
    }
    #pragma unroll
    for (int m = 0; m < Dn; ++m) {
        float a = db2[m];
        #pragma unroll
        for (int j = 0; j < Hn; ++j) a = fmaf(dw2[m*Hn + j], h2[j], a);
        ot[s * Dn + m] = a;
    }
    __syncthreads();

    float4* og = reinterpret_cast<float4*>(xpred + (size_t)blockIdx.x * TILE_F);
    const float4* ot4 = reinterpret_cast<const float4*>(ot);
    #pragma unroll
    for (int i = s; i < TILE_F4; i += 256) og[i] = ot4[i];
}

extern "C" void kernel_launch(void* const* d_in, const int* in_sizes, int n_in,
                              void* d_out, int out_size, void* d_ws, size_t ws_size,
                              hipStream_t stream)
{
    const float* x   = (const float*)d_in[0];
    // d_in[1] = t_span: only its length (T=64) matters; unused at runtime.
    const float* ew1 = (const float*)d_in[2];
    const float* eb1 = (const float*)d_in[3];
    const float* eg  = (const float*)d_in[4];
    const float* ebb = (const float*)d_in[5];
    const float* em  = (const float*)d_in[6];
    const float* ev  = (const float*)d_in[7];
    const float* ew2 = (const float*)d_in[8];
    const float* eb2 = (const float*)d_in[9];
    const float* dw1 = (const float*)d_in[10];
    const float* db1 = (const float*)d_in[11];
    const float* dg  = (const float*)d_in[12];
    const float* dbn = (const float*)d_in[13];
    const float* dm  = (const float*)d_in[14];
    const float* dv  = (const float*)d_in[15];
    const float* dw2 = (const float*)d_in[16];
    const float* db2 = (const float*)d_in[17];
    const float* ow1 = (const float*)d_in[18];
    const float* ob1 = (const float*)d_in[19];
    const float* ow2 = (const float*)d_in[20];
    const float* ob2 = (const float*)d_in[21];
    const float* cw1 = (const float*)d_in[22];
    const float* cb1 = (const float*)d_in[23];
    const float* cw2 = (const float*)d_in[24];
    const float* cb2 = (const float*)d_in[25];

    float* out   = (float*)d_out;
    float* xrec  = out;
    float* xpred = out + OFF_XP;
    float* prob  = out + OFF_PROB;
    float* zseq  = out + OFF_ZS;

    // z-trajectory scratch: prefer d_ws ([t][B][3], coalesced K2 stores);
    // fall back to stashing inside x_pred rows if ws is too small.
    const size_t zbytes = (size_t)Bn * Tn * Ln * sizeof(float);
    float* zscr; int zlayout;
    if (ws_size >= zbytes) { zscr = (float*)d_ws; zlayout = 0; }
    else                   { zscr = xpred;        zlayout = 1; }

    k1_encdec<<<dim3(Bn), dim3(Sn), 0, stream>>>(
        x, ew1, eb1, eg, ebb, em, ev, ew2, eb2,
        dw1, db1, dg, dbn, dm, dv, dw2, db2,
        cw1, cb1, cw2, cb2, xrec, prob, zseq);

    k2_ode<<<dim3(Bn / 256), dim3(256), 0, stream>>>(
        zseq, ow1, ob1, ow2, ob2, zscr, zlayout);

    k3_decpred<<<dim3((Bn * Tn) / 256), dim3(256), 0, stream>>>(
        dw1, db1, dg, dbn, dm, dv, dw2, db2, zscr, zlayout, xpred);
}